// Round 15
// baseline (123.236 us; speedup 1.0000x reference)
//
#include <hip/hip_runtime.h>
#include <hip/hip_bf16.h>

typedef __attribute__((ext_vector_type(8))) short bf16x8;
typedef __attribute__((ext_vector_type(4))) float f32x4;
typedef __attribute__((ext_vector_type(16))) float f32x16;
typedef __attribute__((ext_vector_type(2))) unsigned int u32x2;

#define S_LEN 2048
#define DMODEL 2048
#define NHEAD 32
#define NKVH 8
#define HDIM 64
#define EQKV 3072
// K pre-scale: (1/sqrt(64))*log2(e) so attn uses exp2 directly.
#define KSCALE 0.18033688011112042f

#if defined(__has_builtin)
#if __has_builtin(__builtin_amdgcn_global_load_lds)
#define HAVE_GLL 1
#endif
#endif

__device__ __forceinline__ unsigned short f2bf(float f) {
  unsigned int u = __float_as_uint(f);
  u = (u + 0x7FFFu + ((u >> 16) & 1u)) >> 16;
  return (unsigned short)u;
}

__device__ __forceinline__ f32x4 mfma16(bf16x8 a, bf16x8 b, f32x4 c) {
  return __builtin_amdgcn_mfma_f32_16x16x32_bf16(a, b, c, 0, 0, 0);
}
__device__ __forceinline__ f32x16 mfma32(bf16x8 a, bf16x8 b, f32x16 c) {
  return __builtin_amdgcn_mfma_f32_32x32x16_bf16(a, b, c, 0, 0, 0);
}

__device__ __forceinline__ unsigned cvtpk(float a, float b) {
  unsigned r;
  asm("v_cvt_pk_bf16_f32 %0, %1, %2" : "=v"(r) : "v"(a), "v"(b));
  return r;
}

// lane l's upper/lower-32 exchange without the LDS path (T12 primitive).
__device__ __forceinline__ void plswap(unsigned& a, unsigned& b) {
  u32x2 r = __builtin_amdgcn_permlane32_swap(a, b, false, false);
  a = r.x;
  b = r.y;
}
__device__ __forceinline__ void plswapf(float& a, float& b) {
  unsigned ua = __float_as_uint(a), ub = __float_as_uint(b);
  plswap(ua, ub);
  a = __uint_as_float(ua);
  b = __uint_as_float(ub);
}

#if HAVE_GLL
__device__ __forceinline__ void gload16(const unsigned short* g,
                                        unsigned short* l) {
  __builtin_amdgcn_global_load_lds(
      (const __attribute__((address_space(1))) unsigned int*)g,
      (__attribute__((address_space(3))) unsigned int*)l, 16, 0, 0);
}
#endif

// One launch casts all three f32 buffers to bf16 (x, wqkv, wo).
__global__ void cast3_kernel(const float* __restrict__ x,
                             const float* __restrict__ wqkv,
                             const float* __restrict__ wo,
                             unsigned short* __restrict__ xb,
                             unsigned short* __restrict__ wb,
                             unsigned short* __restrict__ wob) {
  int i = blockIdx.x * blockDim.x + threadIdx.x;
  const float* s;
  unsigned short* d;
  int j;
  if (i < 1048576) {
    s = x; d = xb; j = i;
  } else if (i < 2621440) {
    s = wqkv; d = wb; j = i - 1048576;
  } else {
    s = wo; d = wob; j = i - 2621440;
  }
  float4 v = ((const float4*)s)[j];
  ushort4 o;
  o.x = f2bf(v.x); o.y = f2bf(v.y); o.z = f2bf(v.z); o.w = f2bf(v.w);
  ((ushort4*)d)[j] = o;
}

// C[M][N] = A[M][K] * B[N][K]^T, bf16 in. BMx64 tile, 4 waves.
// BM=128 (QKV gemm), BM=64 (AO gemm; 1024 blocks -> 4-5/CU, round-8 win).
// v15, MODE 1: DEPTH-2 counted-vmcnt pipeline (T4 generalized). gemm1 is
// latency-bound (MfmaUtil 24%, HBM 28%, 2-3 blocks/CU): per-step compute
// ~300cy vs HBM miss ~900cy, so depth-1 covers only 1/3. Now 3 LDS
// buffers (72 KB -> 2 blocks/CU); stage tile t+2 while computing t;
// steady-state vmcnt(12) = 6 loads/stage x 2 tiles in flight across
// barriers; tail drains 6 -> 0. gemm2 stays depth-1 (BM=64, 5 blocks/CU).
// MODE 1 epilogues (unchanged, bit-identical):
//  - Q/K: LDS-transpose rope (coalesced sweep; rope pair = adjacent LDS
//    floats; packed u32 stores). Replicates rope_split verbatim.
//  - V (bn 40..47): fragment-tiled vft written directly; each acc[m][n]
//    is ONE aligned 8B ushort4 store.
// [round-9 lesson: BM=64 on QKV doubled HBM fetch; stay 128.]
// Keeps: raw s_barrier, T1 XCD-chunked swizzle, m97 global_load_lds w=16
// staging, pre-swizzled source chunks (^ row&7).
template <int MODE, int BM, int MINW>
__launch_bounds__(256, MINW)
__global__ void gemm_bt(const unsigned short* __restrict__ A,
                        const unsigned short* __restrict__ B,
                        float* __restrict__ C,
                        unsigned short* __restrict__ VFT,
                        const float* __restrict__ cosb,
                        const float* __restrict__ sinb,
                        unsigned short* __restrict__ qb,
                        unsigned short* __restrict__ kft,
                        int M, int N, int K) {
  constexpr int MF = BM / 32;          // m-fragments per wave
  constexpr int AI = BM / 32;          // A staging iters (BM*8 chunks / 256)
  constexpr int NBUF = (MODE == 1) ? 3 : 2;  // pipeline depth+1
  constexpr int BUFSZ = BM * 64 + 64 * 64;   // shorts per buffer (A then B)
  __shared__ unsigned short smem[NBUF * BUFSZ];
  const int tid = threadIdx.x;
  const int w = tid >> 6, l = tid & 63;
  const int wr = w >> 1, wc = w & 1;
  // T1: XCD-chunked swizzle of the linear block id (nwg % 8 == 0).
  const int nwg = gridDim.x * gridDim.y;
  const int bid0 = blockIdx.y * gridDim.x + blockIdx.x;
  const int swz = (bid0 & 7) * (nwg >> 3) + (bid0 >> 3);
  const int bm = swz / gridDim.x, bn = swz % gridDim.x;
  const int lr = l & 15, lq = l >> 4;

  f32x4 acc[MF][2];
#pragma unroll
  for (int m = 0; m < MF; ++m)
#pragma unroll
    for (int n = 0; n < 2; ++n) acc[m][n] = (f32x4)0.f;

  // per-issue global srcs (chunk c = i*256 + tid; row=c>>3, src=(c&7)^(row&7))
  const unsigned short* gA[AI];
  const unsigned short* gB[2];
#pragma unroll
  for (int i = 0; i < AI; ++i) {
    int c = i * 256 + tid;
    int row = c >> 3;
    int sc = (c & 7) ^ (row & 7);
    gA[i] = A + (size_t)(bm * BM + row) * K + sc * 8;
  }
#pragma unroll
  for (int i = 0; i < 2; ++i) {
    int c = i * 256 + tid;
    int row = c >> 3;
    int sc = (c & 7) ^ (row & 7);
    gB[i] = B + (size_t)(bn * 64 + row) * K + sc * 8;
  }

#if HAVE_GLL
#define STAGE(bufi, k0)                                                  \
  do {                                                                   \
    unsigned short* ab = smem + (bufi) * BUFSZ;                          \
    unsigned short* bb = ab + BM * 64;                                   \
    _Pragma("unroll") for (int i = 0; i < AI; ++i)                       \
        gload16(gA[i] + (k0), ab + (i * 256 + w * 64) * 8);              \
    _Pragma("unroll") for (int i = 0; i < 2; ++i)                        \
        gload16(gB[i] + (k0), bb + (i * 256 + w * 64) * 8);              \
  } while (0)
#else
#define STAGE(bufi, k0)                                                  \
  do {                                                                   \
    unsigned short* ab = smem + (bufi) * BUFSZ;                          \
    unsigned short* bb = ab + BM * 64;                                   \
    _Pragma("unroll") for (int i = 0; i < AI; ++i) {                     \
      int c = i * 256 + tid;                                             \
      *(uint4*)(ab + c * 8) = *(const uint4*)(gA[i] + (k0));             \
    }                                                                    \
    _Pragma("unroll") for (int i = 0; i < 2; ++i) {                      \
      int c = i * 256 + tid;                                             \
      *(uint4*)(bb + c * 8) = *(const uint4*)(gB[i] + (k0));             \
    }                                                                    \
  } while (0)
#endif

#define COMPUTE(bufi)                                                     \
  do {                                                                    \
    const unsigned short* ab = smem + (bufi) * BUFSZ;                     \
    const unsigned short* bb = ab + BM * 64;                              \
    _Pragma("unroll") for (int ks = 0; ks < 2; ++ks) {                    \
      bf16x8 af[MF], bfr[2];                                              \
      _Pragma("unroll") for (int m = 0; m < MF; ++m) {                    \
        int row = wr * (BM / 2) + m * 16 + lr;                            \
        int ch = (ks * 4 + lq) ^ (row & 7);                               \
        af[m] = *(const bf16x8*)(ab + row * 64 + ch * 8);                 \
      }                                                                   \
      _Pragma("unroll") for (int n = 0; n < 2; ++n) {                     \
        int row = wc * 32 + n * 16 + lr;                                  \
        int ch = (ks * 4 + lq) ^ (row & 7);                               \
        bfr[n] = *(const bf16x8*)(bb + row * 64 + ch * 8);                \
      }                                                                   \
      _Pragma("unroll") for (int m = 0; m < MF; ++m)                      \
          _Pragma("unroll") for (int n = 0; n < 2; ++n)                   \
              acc[m][n] = mfma16(af[m], bfr[n], acc[m][n]);               \
    }                                                                     \
  } while (0)

  const int nt = K >> 6;  // k-steps of 64
#if HAVE_GLL
  if constexpr (NBUF == 3) {
    // ---- depth-2 pipeline: two tiles in flight across barriers ----
    STAGE(0, 0);
    STAGE(1, 64);
    int ca = 0, cb = 1, cc = 2;
    for (int t = 0; t < nt - 2; ++t) {
      STAGE(cc, (t + 2) * 64);
      // wait tile t's 6 loads; tiles t+1,t+2 (12) stay outstanding
      asm volatile("s_waitcnt vmcnt(12)" ::: "memory");
      __builtin_amdgcn_sched_barrier(0);
      __builtin_amdgcn_s_barrier();
      COMPUTE(ca);
      asm volatile("s_waitcnt lgkmcnt(0)" ::: "memory");
      __builtin_amdgcn_sched_barrier(0);
      __builtin_amdgcn_s_barrier();
      int tmp = ca; ca = cb; cb = cc; cc = tmp;
    }
    asm volatile("s_waitcnt vmcnt(6)" ::: "memory");
    __builtin_amdgcn_sched_barrier(0);
    __builtin_amdgcn_s_barrier();
    COMPUTE(ca);
    asm volatile("s_waitcnt vmcnt(0)" ::: "memory");
    __builtin_amdgcn_sched_barrier(0);
    __builtin_amdgcn_s_barrier();
    COMPUTE(cb);
  } else {
    // ---- depth-1 pipeline (gemm2) ----
    STAGE(0, 0);
    int cur = 0;
    for (int t = 0; t < nt - 1; ++t) {
      STAGE(cur ^ 1, (t + 1) * 64);
      asm volatile("s_waitcnt vmcnt(4)" ::: "memory");
      __builtin_amdgcn_sched_barrier(0);
      __builtin_amdgcn_s_barrier();
      COMPUTE(cur);
      asm volatile("s_waitcnt lgkmcnt(0)" ::: "memory");
      __builtin_amdgcn_sched_barrier(0);
      __builtin_amdgcn_s_barrier();
      cur ^= 1;
    }
    asm volatile("s_waitcnt vmcnt(0)" ::: "memory");
    __builtin_amdgcn_sched_barrier(0);
    __builtin_amdgcn_s_barrier();
    COMPUTE(cur);
  }
#else
  {
    STAGE(0, 0);
    int cur = 0;
    for (int t = 0; t < nt; ++t) {
      if (t > 0) STAGE(cur, t * 64);
      __syncthreads();
      COMPUTE(cur);
      __syncthreads();
      cur ^= 1;
      if (cur >= 2) cur = 0;
    }
  }
#endif
#undef STAGE
#undef COMPUTE

  const int r0 = bm * BM + wr * (BM / 2);
  const int c0 = bn * 64 + wc * 32;
  if constexpr (MODE == 1) {
    if (bn < 40) {
      // ---- LDS-transpose rope epilogue (Q: bn<32; K: bn 32..39) ----
      __syncthreads();  // all K-loop LDS reads retired
      float (*eps)[66] = (float (*)[66])smem;  // 128x66 f32 = 33.8 KB
#pragma unroll
      for (int m = 0; m < MF; ++m)
#pragma unroll
        for (int n = 0; n < 2; ++n)
#pragma unroll
          for (int r = 0; r < 4; ++r)
            eps[wr * (BM / 2) + m * 16 + 4 * lq + r]
               [wc * 32 + n * 16 + lr] = acc[m][n][r];
      __syncthreads();
      const bool isK = (bn >= 32);
#pragma unroll
      for (int i = 0; i < 16; ++i) {
        const int p = i * 256 + tid;   // 0..4095: (row, pair)
        const int sl = p >> 5, mp = p & 31;
        float tr = eps[sl][2 * mp];
        float ti = eps[sl][2 * mp + 1];
        const int s = bm * BM + sl;
        float c = cosb[s * 32 + mp];
        float sn = sinb[s * 32 + mp];
        if (isK) { c *= KSCALE; sn *= KSCALE; }  // = rope_split's cs/ss
        unsigned u = cvtpk(tr * c - ti * sn, tr * sn + ti * c);
        if (!isK) {
          *(unsigned*)(qb + ((size_t)bn * S_LEN + s) * HDIM + 2 * mp) = u;
        } else {
          const int d = 2 * mp;  // even: (d, d+1) share a 16B kft slot
          *(unsigned*)(kft +
                       ((((size_t)(bn - 32) * 64 + (s >> 5)) * 4 +
                         (d >> 4)) * 64 + (s & 31) + 32 * ((d >> 3) & 1)) *
                           8 + (d & 7)) = u;
        }
      }
    } else {
      // ---- V columns -> fragment-tiled vft DIRECTLY (bn 40..47) ----
      // vft[kvh][kt][c][lane]*8+e = V[kt*32+(c&1)*16+8*(lane>>5)+e]
      //                              [d=(c>>1)*32+(lane&31)]
      const int kvh = bn - 40;
#pragma unroll
      for (int m = 0; m < MF; ++m) {
        const int kt = bm * 4 + wr * 2 + (m >> 1);
        const int clo = m & 1;        // (key>>4)&1
#pragma unroll
        for (int n = 0; n < 2; ++n) {
          const int d = wc * 32 + n * 16 + lr;
          ushort4 pk;
          pk.x = f2bf(acc[m][n][0]);
          pk.y = f2bf(acc[m][n][1]);
          pk.z = f2bf(acc[m][n][2]);
          pk.w = f2bf(acc[m][n][3]);
          unsigned short* dst =
              VFT +
              ((((size_t)kvh * 64 + kt) * 4 + (d >> 5) * 2 + clo) * 64 +
               (d & 31) + 32 * (lq >> 1)) * 8 + 4 * (lq & 1);
          *(ushort4*)dst = pk;
        }
      }
    }
  } else {
#pragma unroll
    for (int m = 0; m < MF; ++m)
#pragma unroll
      for (int n = 0; n < 2; ++n)
#pragma unroll
        for (int r = 0; r < 4; ++r)
          C[(size_t)(r0 + m * 16 + 4 * lq + r) * N + c0 + n * 16 + lr] =
              acc[m][n][r];
  }
}

// Flash attention, swapped-operand 32x32 + 4-way split-K per block.
// Block = (head, 32 q-rows); wave wv handles KV tiles kt = wv, wv+4, ...
// XCD-aware block mapping — kvh has exactly 8 values = 8 XCDs; bid&7
// selects kvh so each XCD's private L2 serves only its own 512 KB of K/V
// fragments (~128x reuse). launch_bounds(256,3) (~170 VGPR, no spill,
// 3 blocks/CU); K AND V fragments loaded together at loop top [round-6
// lesson: cap=128 forced VGPR 64 + 42MB spill]. Pair-unrolled (kt, kt+4):
// 16 coalesced loads in flight, ONE merged softmax / 64 keys.
__launch_bounds__(256, 3)
__global__ void attn_kernel(const unsigned short* __restrict__ qb,
                            const unsigned short* __restrict__ kft,
                            const unsigned short* __restrict__ vft,
                            unsigned short* __restrict__ aob) {
  __shared__ float buf[4][64][19];  // [wave][lane][o-half:16|m|l|pad]
  const int tid = threadIdx.x;
  const int wv = tid >> 6, l = tid & 63;
  const int bid = blockIdx.x;           // 2048 blocks
  const int xcd = bid & 7, idx = bid >> 3;   // idx 0..255
  const int h = xcd * 4 + (idx & 3);         // kvh == xcd
  const int qt = 63 - (idx >> 2);            // longest blocks first per XCD
  const int kvh = xcd;
  const int q0 = qt << 5;
  const int lq = l & 31;
  const int hi = l >> 5;
  const int qg = q0 + lq;

  const unsigned short* qrow = qb + ((size_t)h * S_LEN + qg) * HDIM + 8 * hi;
  bf16x8 qf[4];
#pragma unroll
  for (int j = 0; j < 4; ++j) qf[j] = *(const bf16x8*)(qrow + 16 * j);

  const unsigned short* kbase = kft + (size_t)kvh * 64 * 2048;
  const unsigned short* vbase = vft + (size_t)kvh * 64 * 2048;

  f32x16 o0 = (f32x16)0.f, o1 = (f32x16)0.f;
  float mrun = -1e30f, lrun = 0.f;
  const int ntile = qt + 1;

  int kt = wv;
  // ---- paired tiles: a = kt (never diagonal), b = kt+4 ----
  for (; kt + 4 < ntile; kt += 8) {
    const unsigned short* ka = kbase + (size_t)kt * 2048;
    const unsigned short* va = vbase + (size_t)kt * 2048;
    bf16x8 kfa[4], kfb[4], vaa[4], vab[4];
#pragma unroll
    for (int j = 0; j < 4; ++j) {
      kfa[j] = *(const bf16x8*)(ka + 512 * j + l * 8);
      kfb[j] = *(const bf16x8*)(ka + 4 * 2048 + 512 * j + l * 8);
      vaa[j] = *(const bf16x8*)(va + 512 * j + l * 8);
      vab[j] = *(const bf16x8*)(va + 4 * 2048 + 512 * j + l * 8);
    }
    f32x16 sa = (f32x16)0.f, sb = (f32x16)0.f;
    __builtin_amdgcn_s_setprio(1);
#pragma unroll
    for (int j = 0; j < 4; ++j) sa = mfma32(kfa[j], qf[j], sa);
#pragma unroll
    for (int j = 0; j < 4; ++j) sb = mfma32(kfb[j], qf[j], sb);
    __builtin_amdgcn_s_setprio(0);

    float p[32];
#pragma unroll
    for (int r = 0; r < 16; ++r) p[r] = sa[r];
    if (kt + 4 == ntile - 1) {  // tile b is the diagonal tile
#pragma unroll
      for (int r = 0; r < 16; ++r) {
        int key = (kt + 4) * 32 + (r & 3) + 8 * (r >> 2) + 4 * hi;
        p[16 + r] = (key > qg) ? -1e30f : sb[r];
      }
    } else {
#pragma unroll
      for (int r = 0; r < 16; ++r) p[16 + r] = sb[r];
    }
    // single merged max over 64 keys (T17 triples)
    float a0 = fmaxf(fmaxf(p[0], p[1]), p[2]);
    float a1 = fmaxf(fmaxf(p[3], p[4]), p[5]);
    float a2 = fmaxf(fmaxf(p[6], p[7]), p[8]);
    float a3 = fmaxf(fmaxf(p[9], p[10]), p[11]);
    float a4 = fmaxf(fmaxf(p[12], p[13]), p[14]);
    float b0 = fmaxf(fmaxf(p[15], p[16]), p[17]);
    float b1 = fmaxf(fmaxf(p[18], p[19]), p[20]);
    float b2 = fmaxf(fmaxf(p[21], p[22]), p[23]);
    float b3 = fmaxf(fmaxf(p[24], p[25]), p[26]);
    float b4 = fmaxf(fmaxf(p[27], p[28]), p[29]);
    float b5 = fmaxf(p[30], p[31]);
    float mt = fmaxf(fmaxf(fmaxf(fmaxf(a0, a1), fmaxf(a2, a3)),
                           fmaxf(fmaxf(a4, b0), fmaxf(b1, b2))),
                     fmaxf(fmaxf(b3, b4), b5));
    float mto = mt;
    plswapf(mt, mto);
    mt = fmaxf(mt, mto);
    if (!__all(mt - mrun <= 8.f)) {
      float mnew = fmaxf(mrun, mt);
      float al = __builtin_amdgcn_exp2f(mrun - mnew);
      mrun = mnew;
      lrun *= al;
      o0 *= al;
      o1 *= al;
    }
#pragma unroll
    for (int r = 0; r < 32; ++r) p[r] = __builtin_amdgcn_exp2f(p[r] - mrun);
    float s0 = (p[0] + p[1]) + (p[2] + p[3]);
    float s1 = (p[4] + p[5]) + (p[6] + p[7]);
    float s2 = (p[8] + p[9]) + (p[10] + p[11]);
    float s3 = (p[12] + p[13]) + (p[14] + p[15]);
    float s4 = (p[16] + p[17]) + (p[18] + p[19]);
    float s5 = (p[20] + p[21]) + (p[22] + p[23]);
    float s6 = (p[24] + p[25]) + (p[26] + p[27]);
    float s7 = (p[28] + p[29]) + (p[30] + p[31]);
    float ts = ((s0 + s1) + (s2 + s3)) + ((s4 + s5) + (s6 + s7));
    float tso = ts;
    plswapf(ts, tso);
    ts += tso;
    lrun += ts;
    // P -> bf16 B-fragments via cvt_pk + permlane32_swap (T12), both tiles.
    union B8 { unsigned u[4]; bf16x8 v; } pb0a, pb1a, pb0b, pb1b;
    {
      unsigned t0 = cvtpk(p[0], p[1]), t1 = cvtpk(p[4], p[5]);
      plswap(t0, t1);
      pb0a.u[0] = t0; pb0a.u[2] = t1;
    }
    {
      unsigned t0 = cvtpk(p[2], p[3]), t1 = cvtpk(p[6], p[7]);
      plswap(t0, t1);
      pb0a.u[1] = t0; pb0a.u[3] = t1;
    }
    {
      unsigned t0 = cvtpk(p[8], p[9]), t1 = cvtpk(p[12], p[13]);
      plswap(t0, t1);
      pb1a.u[0] = t0; pb1a.u[2] = t1;
    }
    {
      unsigned t0 = cvtpk(p[10], p[11]), t1 = cvtpk(p[14], p[15]);
      plswap(t0, t1);
      pb1a.u[1] = t0; pb1a.u[3] = t1;
    }
    {
      unsigned t0 = cvtpk(p[16], p[17]), t1 = cvtpk(p[20], p[21]);
      plswap(t0, t1);
      pb0b.u[0] = t0; pb0b.u[2] = t1;
    }
    {
      unsigned t0 = cvtpk(p[18], p[19]), t1 = cvtpk(p[22], p[23]);
      plswap(t0, t1);
      pb0b.u[1] = t0; pb0b.u[3] = t1;
    }
    {
      unsigned t0 = cvtpk(p[24], p[25]), t1 = cvtpk(p[28], p[29]);
      plswap(t0, t1);
      pb1b.u[0] = t0; pb1b.u[2] = t1;
    }
    {
      unsigned t0 = cvtpk(p[26], p[27]), t1 = cvtpk(p[30], p[31]);
      plswap(t0, t1);
      pb1b.u[1] = t0; pb1b.u[3] = t1;
    }
    __builtin_amdgcn_s_setprio(1);
    o0 = mfma32(vaa[0], pb0a.v, o0);
    o0 = mfma32(vaa[1], pb1a.v, o0);
    o1 = mfma32(vaa[2], pb0a.v, o1);
    o1 = mfma32(vaa[3], pb1a.v, o1);
    o0 = mfma32(vab[0], pb0b.v, o0);
    o0 = mfma32(vab[1], pb1b.v, o0);
    o1 = mfma32(vab[2], pb0b.v, o1);
    o1 = mfma32(vab[3], pb1b.v, o1);
    __builtin_amdgcn_s_setprio(0);
  }
  // ---- tail: at most one remaining tile ----
  if (kt < ntile) {
    const int key0 = kt << 5;
    const unsigned short* kvt = kbase + (size_t)kt * 2048;
    bf16x8 kf0 = *(const bf16x8*)(kvt + l * 8);
    bf16x8 kf1 = *(const bf16x8*)(kvt + 512 + l * 8);
    bf16x8 kf2 = *(const bf16x8*)(kvt + 1024 + l * 8);
    bf16x8 kf3 = *(const bf16x8*)(kvt + 1536 + l * 8);
    const unsigned short* vvt = vbase + (size_t)kt * 2048;
    bf16x8 va00 = *(const bf16x8*)(vvt + l * 8);
    bf16x8 va01 = *(const bf16x8*)(vvt + 512 + l * 8);
    bf16x8 va10 = *(const bf16x8*)(vvt + 1024 + l * 8);
    bf16x8 va11 = *(const bf16x8*)(vvt + 1536 + l * 8);

    f32x16 s = (f32x16)0.f;
    __builtin_amdgcn_s_setprio(1);
    s = mfma32(kf0, qf[0], s);
    s = mfma32(kf1, qf[1], s);
    s = mfma32(kf2, qf[2], s);
    s = mfma32(kf3, qf[3], s);
    __builtin_amdgcn_s_setprio(0);

    float p[16];
    if (kt == ntile - 1) {  // diagonal tile: causal mask
#pragma unroll
      for (int r = 0; r < 16; ++r) {
        int key = key0 + (r & 3) + 8 * (r >> 2) + 4 * hi;
        p[r] = (key > qg) ? -1e30f : s[r];
      }
    } else {
#pragma unroll
      for (int r = 0; r < 16; ++r) p[r] = s[r];
    }
    float a0 = fmaxf(fmaxf(p[0], p[1]), p[2]);
    float a1 = fmaxf(fmaxf(p[3], p[4]), p[5]);
    float a2 = fmaxf(fmaxf(p[6], p[7]), p[8]);
    float a3 = fmaxf(fmaxf(p[9], p[10]), p[11]);
    float a4 = fmaxf(fmaxf(p[12], p[13]), p[14]);
    float mt = fmaxf(fmaxf(fmaxf(a0, a1), a2), fmaxf(fmaxf(a3, a4), p[15]));
    float mto = mt;
    plswapf(mt, mto);
    mt = fmaxf(mt, mto);
    if (!__all(mt - mrun <= 8.f)) {
      float mnew = fmaxf(mrun, mt);
      float al = __builtin_amdgcn_exp2f(mrun - mnew);
      mrun = mnew;
      lrun *= al;
      o0 *= al;
      o1 *= al;
    }
#pragma unroll
    for (int r = 0; r < 16; ++r) p[r] = __builtin_amdgcn_exp2f(p[r] - mrun);
    float s0 = (p[0] + p[1]) + (p[2] + p[3]);
    float s1 = (p[4] + p[5]) + (p[6] + p[7]);
    float s2 = (p[8] + p[9]) + (p[10] + p[11]);
    float s3 = (p[12] + p[13]) + (p[14] + p[15]);
    float ts = (s0 + s1) + (s2 + s3);
    float tso = ts;
    plswapf(ts, tso);
    ts += tso;
    lrun += ts;
    union B8 { unsigned u[4]; bf16x8 v; } pb0, pb1;
    {
      unsigned t0 = cvtpk(p[0], p[1]), t1 = cvtpk(p[4], p[5]);
      plswap(t0, t1);
      pb0.u[0] = t0; pb0.u[2] = t1;
    }
    {
      unsigned t0 = cvtpk(p[2], p[3]), t1 = cvtpk(p[6], p[7]);
      plswap(t0, t1);
      pb0.u[1] = t0; pb0.u[3] = t1;
    }
    {
      unsigned t0 = cvtpk(p[8], p[9]), t1 = cvtpk(p[12], p[13]);
      plswap(t0, t1);
      pb1.u[0] = t0; pb1.u[2] = t1;
    }
    {
      unsigned t0 = cvtpk(p[10], p[11]), t1 = cvtpk(p[14], p[15]);
      plswap(t0, t1);
      pb1.u[1] = t0; pb1.u[3] = t1;
    }
    __builtin_amdgcn_s_setprio(1);
    o0 = mfma32(va00, pb0.v, o0);
    o0 = mfma32(va01, pb1.v, o0);
    o1 = mfma32(va10, pb0.v, o1);
    o1 = mfma32(va11, pb1.v, o1);
    __builtin_amdgcn_s_setprio(0);
  }

  // ---- two-phase split-K combine (o0 then o1, 19.4 KB LDS) ----
  // o-reg r of o{dh} maps to d = (r&3) + 8*(r>>2) + 4*hi + 32*dh;
  // wave wv combines regs [wv*4, wv*4+4) of each phase.
  {
    union F16 { f32x16 v; f32x4 q[4]; } uu;
    uu.v = o0;
    float* dst = &buf[wv][l][0];
#pragma unroll
    for (int i = 0; i < 4; ++i) *(f32x4*)(dst + 4 * i) = uu.q[i];
    dst[16] = mrun;
    dst[17] = lrun;
  }
  __syncthreads();
  float mfin = -1e30f;
#pragma unroll
  for (int w2 = 0; w2 < 4; ++w2) mfin = fmaxf(mfin, buf[w2][l][16]);
  float lsum = 0.f;
  float scl[4];
#pragma unroll
  for (int w2 = 0; w2 < 4; ++w2) {
    scl[w2] = __builtin_amdgcn_exp2f(buf[w2][l][16] - mfin);
    lsum += buf[w2][l][17] * scl[w2];
  }
  const float inv = 1.f / lsum;
  unsigned short* obase = aob + (size_t)qg * DMODEL + h * 64;
  {
    f32x4 acc = (f32x4)0.f;
#pragma unroll
    for (int w2 = 0; w2 < 4; ++w2)
      acc += *(const f32x4*)&buf[w2][l][wv * 4] * scl[w2];
    unsigned u0 = cvtpk(acc[0] * inv, acc[1] * inv);
    unsigned u1 = cvtpk(acc[2] * inv, acc[3] * inv);
    unsigned short* dsto = obase + 8 * wv + 4 * hi;
    *(unsigned*)(dsto) = u0;
    *(unsigned*)(dsto + 2) = u1;
  }
  __syncthreads();  // all phase-A reads done before overwrite
  {
    union F16 { f32x16 v; f32x4 q[4]; } uu;
    uu.v = o1;
    float* dst = &buf[wv][l][0];
#pragma unroll
    for (int i = 0; i < 4; ++i) *(f32x4*)(dst + 4 * i) = uu.q[i];
  }
  __syncthreads();
  {
    f32x4 acc = (f32x4)0.f;
#pragma unroll
    for (int w2 = 0; w2 < 4; ++w2)
      acc += *(const f32x4*)&buf[w2][l][wv * 4] * scl[w2];
    unsigned u0 = cvtpk(acc[0] * inv, acc[1] * inv);
    unsigned u1 = cvtpk(acc[2] * inv, acc[3] * inv);
    unsigned short* dsto = obase + 32 + 8 * wv + 4 * hi;
    *(unsigned*)(dsto) = u0;
    *(unsigned*)(dsto + 2) = u1;
  }
}

extern "C" void kernel_launch(void* const* d_in, const int* in_sizes, int n_in,
                              void* d_out, int out_size, void* d_ws,
                              size_t ws_size, hipStream_t stream) {
  const float* x = (const float*)d_in[0];
  const float* cosb = (const float*)d_in[1];
  const float* sinb = (const float*)d_in[2];
  const float* wqkv = (const float*)d_in[3];
  const float* wo = (const float*)d_in[4];
  float* out = (float*)d_out;
  char* ws = (char*)d_ws;
  float* qkv = (float*)(ws);                               // (unused now)
  unsigned short* xb = (unsigned short*)(ws + 25165824);   //  8,388,608
  unsigned short* wb = (unsigned short*)(ws + 33554432);   // 12,582,912
  unsigned short* wob = (unsigned short*)(ws + 46137344);  //  8,388,608
  unsigned short* qb = (unsigned short*)(ws + 54525952);   //  8,388,608
  unsigned short* kft = (unsigned short*)(ws + 62914560);  //  2,097,152
  unsigned short* vft = (unsigned short*)(ws + 65011712);  //  2,097,152
  unsigned short* aob = (unsigned short*)(ws + 67108864);  //  8,388,608

  cast3_kernel<<<dim3(3670016 / 256), 256, 0, stream>>>(x, wqkv, wo, xb, wb,
                                                        wob);
  gemm_bt<1, 128, 2><<<dim3(48, 16), 256, 0, stream>>>(
      xb, wb, qkv, vft, cosb, sinb, qb, kft, 2048, 3072, 2048);
  attn_kernel<<<dim3(2048), 256, 0, stream>>>(qb, kft, vft, aob);
  gemm_bt<0, 64, 5><<<dim3(32, 32), 256, 0, stream>>>(
      aob, wob, out, nullptr, nullptr, nullptr, nullptr, nullptr, 2048, 2048,
      2048);
}

// Round 16
// 116.756 us; speedup vs baseline: 1.0555x; 1.0555x over previous
//
#include <hip/hip_runtime.h>
#include <hip/hip_bf16.h>

typedef __attribute__((ext_vector_type(8))) short bf16x8;
typedef __attribute__((ext_vector_type(4))) float f32x4;
typedef __attribute__((ext_vector_type(16))) float f32x16;
typedef __attribute__((ext_vector_type(2))) unsigned int u32x2;

#define S_LEN 2048
#define DMODEL 2048
#define NHEAD 32
#define NKVH 8
#define HDIM 64
#define EQKV 3072
// K pre-scale: (1/sqrt(64))*log2(e) so attn uses exp2 directly.
#define KSCALE 0.18033688011112042f

#if defined(__has_builtin)
#if __has_builtin(__builtin_amdgcn_global_load_lds)
#define HAVE_GLL 1
#endif
#endif

__device__ __forceinline__ unsigned short f2bf(float f) {
  unsigned int u = __float_as_uint(f);
  u = (u + 0x7FFFu + ((u >> 16) & 1u)) >> 16;
  return (unsigned short)u;
}

__device__ __forceinline__ f32x4 mfma16(bf16x8 a, bf16x8 b, f32x4 c) {
  return __builtin_amdgcn_mfma_f32_16x16x32_bf16(a, b, c, 0, 0, 0);
}
__device__ __forceinline__ f32x16 mfma32(bf16x8 a, bf16x8 b, f32x16 c) {
  return __builtin_amdgcn_mfma_f32_32x32x16_bf16(a, b, c, 0, 0, 0);
}

__device__ __forceinline__ unsigned cvtpk(float a, float b) {
  unsigned r;
  asm("v_cvt_pk_bf16_f32 %0, %1, %2" : "=v"(r) : "v"(a), "v"(b));
  return r;
}

// lane l's upper/lower-32 exchange without the LDS path (T12 primitive).
__device__ __forceinline__ void plswap(unsigned& a, unsigned& b) {
  u32x2 r = __builtin_amdgcn_permlane32_swap(a, b, false, false);
  a = r.x;
  b = r.y;
}
__device__ __forceinline__ void plswapf(float& a, float& b) {
  unsigned ua = __float_as_uint(a), ub = __float_as_uint(b);
  plswap(ua, ub);
  a = __uint_as_float(ua);
  b = __uint_as_float(ub);
}

#if HAVE_GLL
__device__ __forceinline__ void gload16(const unsigned short* g,
                                        unsigned short* l) {
  __builtin_amdgcn_global_load_lds(
      (const __attribute__((address_space(1))) unsigned int*)g,
      (__attribute__((address_space(3))) unsigned int*)l, 16, 0, 0);
}
#endif

// One launch casts all three f32 buffers to bf16 (x, wqkv, wo).
__global__ void cast3_kernel(const float* __restrict__ x,
                             const float* __restrict__ wqkv,
                             const float* __restrict__ wo,
                             unsigned short* __restrict__ xb,
                             unsigned short* __restrict__ wb,
                             unsigned short* __restrict__ wob) {
  int i = blockIdx.x * blockDim.x + threadIdx.x;
  const float* s;
  unsigned short* d;
  int j;
  if (i < 1048576) {
    s = x; d = xb; j = i;
  } else if (i < 2621440) {
    s = wqkv; d = wb; j = i - 1048576;
  } else {
    s = wo; d = wob; j = i - 2621440;
  }
  float4 v = ((const float4*)s)[j];
  ushort4 o;
  o.x = f2bf(v.x); o.y = f2bf(v.y); o.z = f2bf(v.z); o.w = f2bf(v.w);
  ((ushort4*)d)[j] = o;
}

// C[M][N] = A[M][K] * B[N][K]^T, bf16 in. BMx64 tile, 4 waves.
// BM=128 (QKV gemm), BM=64 (AO gemm; 1024 blocks -> 4-5/CU, round-8 win).
// v16 = exact revert to the round-14 best (116.9us): depth-1 counted-vmcnt
// pipeline everywhere. [round-15 lesson: depth-2 (3 LDS bufs, 72KB) cut
// occupancy 3->2 blocks/CU and LOST 9us — at this tile, cross-block TLP
// (m114) beats per-wave pipeline depth. round-9 lesson: BM=64 on QKV
// doubled HBM fetch; stay 128.]
// MODE 1 epilogues (bit-identical to reference path):
//  - Q/K (bn<40): LDS-transpose rope — acc -> f32 [128][66] LDS tile,
//    barrier, coalesced sweep (rope pair = adjacent floats, lane-
//    consecutive cos/sin, packed u32 stores). Replicates rope_split.
//  - V (bn 40..47): fragment-tiled vft written directly; each acc[m][n]
//    is ONE aligned 8B ushort4 store.
// Keeps: raw s_barrier, T1 XCD-chunked swizzle, m97 global_load_lds w=16
// staging, pre-swizzled source chunks (^ row&7).
template <int MODE, int BM, int MINW>
__launch_bounds__(256, MINW)
__global__ void gemm_bt(const unsigned short* __restrict__ A,
                        const unsigned short* __restrict__ B,
                        float* __restrict__ C,
                        unsigned short* __restrict__ VFT,
                        const float* __restrict__ cosb,
                        const float* __restrict__ sinb,
                        unsigned short* __restrict__ qb,
                        unsigned short* __restrict__ kft,
                        int M, int N, int K) {
  constexpr int MF = BM / 32;       // m-fragments per wave
  constexpr int AI = BM / 32;       // A staging iters (BM*8 chunks / 256)
  // Unified LDS: staging buffers during the K-loop; for MODE 1 Q/K blocks
  // the space is reused post-loop as a f32 [128][66] transpose tile.
  __shared__ unsigned short smem[2 * BM * 64 + 2 * 64 * 64];
  unsigned short (*As)[BM * 64] = (unsigned short (*)[BM * 64])smem;
  unsigned short (*Bs)[64 * 64] =
      (unsigned short (*)[64 * 64])(smem + 2 * BM * 64);
  const int tid = threadIdx.x;
  const int w = tid >> 6, l = tid & 63;
  const int wr = w >> 1, wc = w & 1;
  // T1: XCD-chunked swizzle of the linear block id (nwg % 8 == 0).
  const int nwg = gridDim.x * gridDim.y;
  const int bid0 = blockIdx.y * gridDim.x + blockIdx.x;
  const int swz = (bid0 & 7) * (nwg >> 3) + (bid0 >> 3);
  const int bm = swz / gridDim.x, bn = swz % gridDim.x;
  const int lr = l & 15, lq = l >> 4;

  f32x4 acc[MF][2];
#pragma unroll
  for (int m = 0; m < MF; ++m)
#pragma unroll
    for (int n = 0; n < 2; ++n) acc[m][n] = (f32x4)0.f;

  // per-issue global srcs (chunk c = i*256 + tid; row=c>>3, src=(c&7)^(row&7))
  const unsigned short* gA[AI];
  const unsigned short* gB[2];
#pragma unroll
  for (int i = 0; i < AI; ++i) {
    int c = i * 256 + tid;
    int row = c >> 3;
    int sc = (c & 7) ^ (row & 7);
    gA[i] = A + (size_t)(bm * BM + row) * K + sc * 8;
  }
#pragma unroll
  for (int i = 0; i < 2; ++i) {
    int c = i * 256 + tid;
    int row = c >> 3;
    int sc = (c & 7) ^ (row & 7);
    gB[i] = B + (size_t)(bn * 64 + row) * K + sc * 8;
  }

#if HAVE_GLL
#define STAGE(bufi, k0)                                            \
  do {                                                             \
    _Pragma("unroll") for (int i = 0; i < AI; ++i)                 \
        gload16(gA[i] + (k0), &As[bufi][(i * 256 + w * 64) * 8]);  \
    _Pragma("unroll") for (int i = 0; i < 2; ++i)                  \
        gload16(gB[i] + (k0), &Bs[bufi][(i * 256 + w * 64) * 8]);  \
  } while (0)
#else
#define STAGE(bufi, k0)                                            \
  do {                                                             \
    _Pragma("unroll") for (int i = 0; i < AI; ++i) {               \
      int c = i * 256 + tid;                                       \
      *(uint4*)(&As[bufi][c * 8]) = *(const uint4*)(gA[i] + (k0)); \
    }                                                              \
    _Pragma("unroll") for (int i = 0; i < 2; ++i) {                \
      int c = i * 256 + tid;                                       \
      *(uint4*)(&Bs[bufi][c * 8]) = *(const uint4*)(gB[i] + (k0)); \
    }                                                              \
  } while (0)
#endif

#define COMPUTE(bufi)                                                     \
  do {                                                                    \
    _Pragma("unroll") for (int ks = 0; ks < 2; ++ks) {                    \
      bf16x8 af[MF], bfr[2];                                              \
      _Pragma("unroll") for (int m = 0; m < MF; ++m) {                    \
        int row = wr * (BM / 2) + m * 16 + lr;                            \
        int ch = (ks * 4 + lq) ^ (row & 7);                               \
        af[m] = *(const bf16x8*)(&As[bufi][row * 64 + ch * 8]);           \
      }                                                                   \
      _Pragma("unroll") for (int n = 0; n < 2; ++n) {                     \
        int row = wc * 32 + n * 16 + lr;                                  \
        int ch = (ks * 4 + lq) ^ (row & 7);                               \
        bfr[n] = *(const bf16x8*)(&Bs[bufi][row * 64 + ch * 8]);          \
      }                                                                   \
      _Pragma("unroll") for (int m = 0; m < MF; ++m)                      \
          _Pragma("unroll") for (int n = 0; n < 2; ++n)                   \
              acc[m][n] = mfma16(af[m], bfr[n], acc[m][n]);               \
    }                                                                     \
  } while (0)

  const int nt = K >> 6;  // k-steps of 64
  STAGE(0, 0);
  int cur = 0;
#if HAVE_GLL
  for (int t = 0; t < nt - 1; ++t) {
    STAGE(cur ^ 1, (t + 1) * 64);  // next tile's loads issued first
    // wait for OWN current-tile loads (next tile's stay outstanding)
    if constexpr (BM == 128)
      asm volatile("s_waitcnt vmcnt(6)" ::: "memory");
    else
      asm volatile("s_waitcnt vmcnt(4)" ::: "memory");
    __builtin_amdgcn_sched_barrier(0);
    __builtin_amdgcn_s_barrier();  // all waves' tile-t loads landed
    COMPUTE(cur);
    // all my LDS reads complete before anyone overwrites this buffer
    asm volatile("s_waitcnt lgkmcnt(0)" ::: "memory");
    __builtin_amdgcn_sched_barrier(0);
    __builtin_amdgcn_s_barrier();
    cur ^= 1;
  }
  asm volatile("s_waitcnt vmcnt(0)" ::: "memory");
  __builtin_amdgcn_sched_barrier(0);
  __builtin_amdgcn_s_barrier();
  COMPUTE(cur);
#else
  for (int t = 0; t < nt; ++t) {
    if (t > 0) STAGE(cur, t * 64);
    __syncthreads();
    COMPUTE(cur);
    __syncthreads();
  }
#endif
#undef STAGE
#undef COMPUTE

  const int r0 = bm * BM + wr * (BM / 2);
  const int c0 = bn * 64 + wc * 32;
  if constexpr (MODE == 1) {
    if (bn < 40) {
      // ---- LDS-transpose rope epilogue (Q: bn<32; K: bn 32..39) ----
      __syncthreads();  // all K-loop LDS reads retired
      float (*eps)[66] = (float (*)[66])smem;  // 128x66 f32 = 33.8 KB
#pragma unroll
      for (int m = 0; m < MF; ++m)
#pragma unroll
        for (int n = 0; n < 2; ++n)
#pragma unroll
          for (int r = 0; r < 4; ++r)
            eps[wr * (BM / 2) + m * 16 + 4 * lq + r]
               [wc * 32 + n * 16 + lr] = acc[m][n][r];
      __syncthreads();
      const bool isK = (bn >= 32);
#pragma unroll
      for (int i = 0; i < 16; ++i) {
        const int p = i * 256 + tid;   // 0..4095: (row, pair)
        const int sl = p >> 5, mp = p & 31;
        float tr = eps[sl][2 * mp];
        float ti = eps[sl][2 * mp + 1];
        const int s = bm * BM + sl;
        float c = cosb[s * 32 + mp];
        float sn = sinb[s * 32 + mp];
        if (isK) { c *= KSCALE; sn *= KSCALE; }  // = rope_split's cs/ss
        unsigned u = cvtpk(tr * c - ti * sn, tr * sn + ti * c);
        if (!isK) {
          *(unsigned*)(qb + ((size_t)bn * S_LEN + s) * HDIM + 2 * mp) = u;
        } else {
          const int d = 2 * mp;  // even: (d, d+1) share a 16B kft slot
          *(unsigned*)(kft +
                       ((((size_t)(bn - 32) * 64 + (s >> 5)) * 4 +
                         (d >> 4)) * 64 + (s & 31) + 32 * ((d >> 3) & 1)) *
                           8 + (d & 7)) = u;
        }
      }
    } else {
      // ---- V columns -> fragment-tiled vft DIRECTLY (bn 40..47) ----
      // vft[kvh][kt][c][lane]*8+e = V[kt*32+(c&1)*16+8*(lane>>5)+e]
      //                              [d=(c>>1)*32+(lane&31)]
      const int kvh = bn - 40;
#pragma unroll
      for (int m = 0; m < MF; ++m) {
        const int kt = bm * 4 + wr * 2 + (m >> 1);
        const int clo = m & 1;        // (key>>4)&1
#pragma unroll
        for (int n = 0; n < 2; ++n) {
          const int d = wc * 32 + n * 16 + lr;
          ushort4 pk;
          pk.x = f2bf(acc[m][n][0]);
          pk.y = f2bf(acc[m][n][1]);
          pk.z = f2bf(acc[m][n][2]);
          pk.w = f2bf(acc[m][n][3]);
          unsigned short* dst =
              VFT +
              ((((size_t)kvh * 64 + kt) * 4 + (d >> 5) * 2 + clo) * 64 +
               (d & 31) + 32 * (lq >> 1)) * 8 + 4 * (lq & 1);
          *(ushort4*)dst = pk;
        }
      }
    }
  } else {
#pragma unroll
    for (int m = 0; m < MF; ++m)
#pragma unroll
      for (int n = 0; n < 2; ++n)
#pragma unroll
        for (int r = 0; r < 4; ++r)
          C[(size_t)(r0 + m * 16 + 4 * lq + r) * N + c0 + n * 16 + lr] =
              acc[m][n][r];
  }
}

// Flash attention, swapped-operand 32x32 + 4-way split-K per block.
// Block = (head, 32 q-rows); wave wv handles KV tiles kt = wv, wv+4, ...
// XCD-aware block mapping — kvh has exactly 8 values = 8 XCDs; bid&7
// selects kvh so each XCD's private L2 serves only its own 512 KB of K/V
// fragments (~128x reuse). launch_bounds(256,3) (~170 VGPR, no spill,
// 3 blocks/CU); K AND V fragments loaded together at loop top [round-6
// lesson: cap=128 forced VGPR 64 + 42MB spill]. Pair-unrolled (kt, kt+4):
// 16 coalesced loads in flight, ONE merged softmax / 64 keys.
__launch_bounds__(256, 3)
__global__ void attn_kernel(const unsigned short* __restrict__ qb,
                            const unsigned short* __restrict__ kft,
                            const unsigned short* __restrict__ vft,
                            unsigned short* __restrict__ aob) {
  __shared__ float buf[4][64][19];  // [wave][lane][o-half:16|m|l|pad]
  const int tid = threadIdx.x;
  const int wv = tid >> 6, l = tid & 63;
  const int bid = blockIdx.x;           // 2048 blocks
  const int xcd = bid & 7, idx = bid >> 3;   // idx 0..255
  const int h = xcd * 4 + (idx & 3);         // kvh == xcd
  const int qt = 63 - (idx >> 2);            // longest blocks first per XCD
  const int kvh = xcd;
  const int q0 = qt << 5;
  const int lq = l & 31;
  const int hi = l >> 5;
  const int qg = q0 + lq;

  const unsigned short* qrow = qb + ((size_t)h * S_LEN + qg) * HDIM + 8 * hi;
  bf16x8 qf[4];
#pragma unroll
  for (int j = 0; j < 4; ++j) qf[j] = *(const bf16x8*)(qrow + 16 * j);

  const unsigned short* kbase = kft + (size_t)kvh * 64 * 2048;
  const unsigned short* vbase = vft + (size_t)kvh * 64 * 2048;

  f32x16 o0 = (f32x16)0.f, o1 = (f32x16)0.f;
  float mrun = -1e30f, lrun = 0.f;
  const int ntile = qt + 1;

  int kt = wv;
  // ---- paired tiles: a = kt (never diagonal), b = kt+4 ----
  for (; kt + 4 < ntile; kt += 8) {
    const unsigned short* ka = kbase + (size_t)kt * 2048;
    const unsigned short* va = vbase + (size_t)kt * 2048;
    bf16x8 kfa[4], kfb[4], vaa[4], vab[4];
#pragma unroll
    for (int j = 0; j < 4; ++j) {
      kfa[j] = *(const bf16x8*)(ka + 512 * j + l * 8);
      kfb[j] = *(const bf16x8*)(ka + 4 * 2048 + 512 * j + l * 8);
      vaa[j] = *(const bf16x8*)(va + 512 * j + l * 8);
      vab[j] = *(const bf16x8*)(va + 4 * 2048 + 512 * j + l * 8);
    }
    f32x16 sa = (f32x16)0.f, sb = (f32x16)0.f;
    __builtin_amdgcn_s_setprio(1);
#pragma unroll
    for (int j = 0; j < 4; ++j) sa = mfma32(kfa[j], qf[j], sa);
#pragma unroll
    for (int j = 0; j < 4; ++j) sb = mfma32(kfb[j], qf[j], sb);
    __builtin_amdgcn_s_setprio(0);

    float p[32];
#pragma unroll
    for (int r = 0; r < 16; ++r) p[r] = sa[r];
    if (kt + 4 == ntile - 1) {  // tile b is the diagonal tile
#pragma unroll
      for (int r = 0; r < 16; ++r) {
        int key = (kt + 4) * 32 + (r & 3) + 8 * (r >> 2) + 4 * hi;
        p[16 + r] = (key > qg) ? -1e30f : sb[r];
      }
    } else {
#pragma unroll
      for (int r = 0; r < 16; ++r) p[16 + r] = sb[r];
    }
    // single merged max over 64 keys (T17 triples)
    float a0 = fmaxf(fmaxf(p[0], p[1]), p[2]);
    float a1 = fmaxf(fmaxf(p[3], p[4]), p[5]);
    float a2 = fmaxf(fmaxf(p[6], p[7]), p[8]);
    float a3 = fmaxf(fmaxf(p[9], p[10]), p[11]);
    float a4 = fmaxf(fmaxf(p[12], p[13]), p[14]);
    float b0 = fmaxf(fmaxf(p[15], p[16]), p[17]);
    float b1 = fmaxf(fmaxf(p[18], p[19]), p[20]);
    float b2 = fmaxf(fmaxf(p[21], p[22]), p[23]);
    float b3 = fmaxf(fmaxf(p[24], p[25]), p[26]);
    float b4 = fmaxf(fmaxf(p[27], p[28]), p[29]);
    float b5 = fmaxf(p[30], p[31]);
    float mt = fmaxf(fmaxf(fmaxf(fmaxf(a0, a1), fmaxf(a2, a3)),
                           fmaxf(fmaxf(a4, b0), fmaxf(b1, b2))),
                     fmaxf(fmaxf(b3, b4), b5));
    float mto = mt;
    plswapf(mt, mto);
    mt = fmaxf(mt, mto);
    if (!__all(mt - mrun <= 8.f)) {
      float mnew = fmaxf(mrun, mt);
      float al = __builtin_amdgcn_exp2f(mrun - mnew);
      mrun = mnew;
      lrun *= al;
      o0 *= al;
      o1 *= al;
    }
#pragma unroll
    for (int r = 0; r < 32; ++r) p[r] = __builtin_amdgcn_exp2f(p[r] - mrun);
    float s0 = (p[0] + p[1]) + (p[2] + p[3]);
    float s1 = (p[4] + p[5]) + (p[6] + p[7]);
    float s2 = (p[8] + p[9]) + (p[10] + p[11]);
    float s3 = (p[12] + p[13]) + (p[14] + p[15]);
    float s4 = (p[16] + p[17]) + (p[18] + p[19]);
    float s5 = (p[20] + p[21]) + (p[22] + p[23]);
    float s6 = (p[24] + p[25]) + (p[26] + p[27]);
    float s7 = (p[28] + p[29]) + (p[30] + p[31]);
    float ts = ((s0 + s1) + (s2 + s3)) + ((s4 + s5) + (s6 + s7));
    float tso = ts;
    plswapf(ts, tso);
    ts += tso;
    lrun += ts;
    // P -> bf16 B-fragments via cvt_pk + permlane32_swap (T12), both tiles.
    union B8 { unsigned u[4]; bf16x8 v; } pb0a, pb1a, pb0b, pb1b;
    {
      unsigned t0 = cvtpk(p[0], p[1]), t1 = cvtpk(p[4], p[5]);
      plswap(t0, t1);
      pb0a.u[0] = t0; pb0a.u[2] = t1;
    }
    {
      unsigned t0 = cvtpk(p[2], p[3]), t1 = cvtpk(p[6], p[7]);
      plswap(t0, t1);
      pb0a.u[1] = t0; pb0a.u[3] = t1;
    }
    {
      unsigned t0 = cvtpk(p[8], p[9]), t1 = cvtpk(p[12], p[13]);
      plswap(t0, t1);
      pb1a.u[0] = t0; pb1a.u[2] = t1;
    }
    {
      unsigned t0 = cvtpk(p[10], p[11]), t1 = cvtpk(p[14], p[15]);
      plswap(t0, t1);
      pb1a.u[1] = t0; pb1a.u[3] = t1;
    }
    {
      unsigned t0 = cvtpk(p[16], p[17]), t1 = cvtpk(p[20], p[21]);
      plswap(t0, t1);
      pb0b.u[0] = t0; pb0b.u[2] = t1;
    }
    {
      unsigned t0 = cvtpk(p[18], p[19]), t1 = cvtpk(p[22], p[23]);
      plswap(t0, t1);
      pb0b.u[1] = t0; pb0b.u[3] = t1;
    }
    {
      unsigned t0 = cvtpk(p[24], p[25]), t1 = cvtpk(p[28], p[29]);
      plswap(t0, t1);
      pb1b.u[0] = t0; pb1b.u[2] = t1;
    }
    {
      unsigned t0 = cvtpk(p[26], p[27]), t1 = cvtpk(p[30], p[31]);
      plswap(t0, t1);
      pb1b.u[1] = t0; pb1b.u[3] = t1;
    }
    __builtin_amdgcn_s_setprio(1);
    o0 = mfma32(vaa[0], pb0a.v, o0);
    o0 = mfma32(vaa[1], pb1a.v, o0);
    o1 = mfma32(vaa[2], pb0a.v, o1);
    o1 = mfma32(vaa[3], pb1a.v, o1);
    o0 = mfma32(vab[0], pb0b.v, o0);
    o0 = mfma32(vab[1], pb1b.v, o0);
    o1 = mfma32(vab[2], pb0b.v, o1);
    o1 = mfma32(vab[3], pb1b.v, o1);
    __builtin_amdgcn_s_setprio(0);
  }
  // ---- tail: at most one remaining tile ----
  if (kt < ntile) {
    const int key0 = kt << 5;
    const unsigned short* kvt = kbase + (size_t)kt * 2048;
    bf16x8 kf0 = *(const bf16x8*)(kvt + l * 8);
    bf16x8 kf1 = *(const bf16x8*)(kvt + 512 + l * 8);
    bf16x8 kf2 = *(const bf16x8*)(kvt + 1024 + l * 8);
    bf16x8 kf3 = *(const bf16x8*)(kvt + 1536 + l * 8);
    const unsigned short* vvt = vbase + (size_t)kt * 2048;
    bf16x8 va00 = *(const bf16x8*)(vvt + l * 8);
    bf16x8 va01 = *(const bf16x8*)(vvt + 512 + l * 8);
    bf16x8 va10 = *(const bf16x8*)(vvt + 1024 + l * 8);
    bf16x8 va11 = *(const bf16x8*)(vvt + 1536 + l * 8);

    f32x16 s = (f32x16)0.f;
    __builtin_amdgcn_s_setprio(1);
    s = mfma32(kf0, qf[0], s);
    s = mfma32(kf1, qf[1], s);
    s = mfma32(kf2, qf[2], s);
    s = mfma32(kf3, qf[3], s);
    __builtin_amdgcn_s_setprio(0);

    float p[16];
    if (kt == ntile - 1) {  // diagonal tile: causal mask
#pragma unroll
      for (int r = 0; r < 16; ++r) {
        int key = key0 + (r & 3) + 8 * (r >> 2) + 4 * hi;
        p[r] = (key > qg) ? -1e30f : s[r];
      }
    } else {
#pragma unroll
      for (int r = 0; r < 16; ++r) p[r] = s[r];
    }
    float a0 = fmaxf(fmaxf(p[0], p[1]), p[2]);
    float a1 = fmaxf(fmaxf(p[3], p[4]), p[5]);
    float a2 = fmaxf(fmaxf(p[6], p[7]), p[8]);
    float a3 = fmaxf(fmaxf(p[9], p[10]), p[11]);
    float a4 = fmaxf(fmaxf(p[12], p[13]), p[14]);
    float mt = fmaxf(fmaxf(fmaxf(a0, a1), a2), fmaxf(fmaxf(a3, a4), p[15]));
    float mto = mt;
    plswapf(mt, mto);
    mt = fmaxf(mt, mto);
    if (!__all(mt - mrun <= 8.f)) {
      float mnew = fmaxf(mrun, mt);
      float al = __builtin_amdgcn_exp2f(mrun - mnew);
      mrun = mnew;
      lrun *= al;
      o0 *= al;
      o1 *= al;
    }
#pragma unroll
    for (int r = 0; r < 16; ++r) p[r] = __builtin_amdgcn_exp2f(p[r] - mrun);
    float s0 = (p[0] + p[1]) + (p[2] + p[3]);
    float s1 = (p[4] + p[5]) + (p[6] + p[7]);
    float s2 = (p[8] + p[9]) + (p[10] + p[11]);
    float s3 = (p[12] + p[13]) + (p[14] + p[15]);
    float ts = (s0 + s1) + (s2 + s3);
    float tso = ts;
    plswapf(ts, tso);
    ts += tso;
    lrun += ts;
    union B8 { unsigned u[4]; bf16x8 v; } pb0, pb1;
    {
      unsigned t0 = cvtpk(p[0], p[1]), t1 = cvtpk(p[4], p[5]);
      plswap(t0, t1);
      pb0.u[0] = t0; pb0.u[2] = t1;
    }
    {
      unsigned t0 = cvtpk(p[2], p[3]), t1 = cvtpk(p[6], p[7]);
      plswap(t0, t1);
      pb0.u[1] = t0; pb0.u[3] = t1;
    }
    {
      unsigned t0 = cvtpk(p[8], p[9]), t1 = cvtpk(p[12], p[13]);
      plswap(t0, t1);
      pb1.u[0] = t0; pb1.u[2] = t1;
    }
    {
      unsigned t0 = cvtpk(p[10], p[11]), t1 = cvtpk(p[14], p[15]);
      plswap(t0, t1);
      pb1.u[1] = t0; pb1.u[3] = t1;
    }
    __builtin_amdgcn_s_setprio(1);
    o0 = mfma32(va00, pb0.v, o0);
    o0 = mfma32(va01, pb1.v, o0);
    o1 = mfma32(va10, pb0.v, o1);
    o1 = mfma32(va11, pb1.v, o1);
    __builtin_amdgcn_s_setprio(0);
  }

  // ---- two-phase split-K combine (o0 then o1, 19.4 KB LDS) ----
  // o-reg r of o{dh} maps to d = (r&3) + 8*(r>>2) + 4*hi + 32*dh;
  // wave wv combines regs [wv*4, wv*4+4) of each phase.
  {
    union F16 { f32x16 v; f32x4 q[4]; } uu;
    uu.v = o0;
    float* dst = &buf[wv][l][0];
#pragma unroll
    for (int i = 0; i < 4; ++i) *(f32x4*)(dst + 4 * i) = uu.q[i];
    dst[16] = mrun;
    dst[17] = lrun;
  }
  __syncthreads();
  float mfin = -1e30f;
#pragma unroll
  for (int w2 = 0; w2 < 4; ++w2) mfin = fmaxf(mfin, buf[w2][l][16]);
  float lsum = 0.f;
  float scl[4];
#pragma unroll
  for (int w2 = 0; w2 < 4; ++w2) {
    scl[w2] = __builtin_amdgcn_exp2f(buf[w2][l][16] - mfin);
    lsum += buf[w2][l][17] * scl[w2];
  }
  const float inv = 1.f / lsum;
  unsigned short* obase = aob + (size_t)qg * DMODEL + h * 64;
  {
    f32x4 acc = (f32x4)0.f;
#pragma unroll
    for (int w2 = 0; w2 < 4; ++w2)
      acc += *(const f32x4*)&buf[w2][l][wv * 4] * scl[w2];
    unsigned u0 = cvtpk(acc[0] * inv, acc[1] * inv);
    unsigned u1 = cvtpk(acc[2] * inv, acc[3] * inv);
    unsigned short* dsto = obase + 8 * wv + 4 * hi;
    *(unsigned*)(dsto) = u0;
    *(unsigned*)(dsto + 2) = u1;
  }
  __syncthreads();  // all phase-A reads done before overwrite
  {
    union F16 { f32x16 v; f32x4 q[4]; } uu;
    uu.v = o1;
    float* dst = &buf[wv][l][0];
#pragma unroll
    for (int i = 0; i < 4; ++i) *(f32x4*)(dst + 4 * i) = uu.q[i];
  }
  __syncthreads();
  {
    f32x4 acc = (f32x4)0.f;
#pragma unroll
    for (int w2 = 0; w2 < 4; ++w2)
      acc += *(const f32x4*)&buf[w2][l][wv * 4] * scl[w2];
    unsigned u0 = cvtpk(acc[0] * inv, acc[1] * inv);
    unsigned u1 = cvtpk(acc[2] * inv, acc[3] * inv);
    unsigned short* dsto = obase + 32 + 8 * wv + 4 * hi;
    *(unsigned*)(dsto) = u0;
    *(unsigned*)(dsto + 2) = u1;
  }
}

extern "C" void kernel_launch(void* const* d_in, const int* in_sizes, int n_in,
                              void* d_out, int out_size, void* d_ws,
                              size_t ws_size, hipStream_t stream) {
  const float* x = (const float*)d_in[0];
  const float* cosb = (const float*)d_in[1];
  const float* sinb = (const float*)d_in[2];
  const float* wqkv = (const float*)d_in[3];
  const float* wo = (const float*)d_in[4];
  float* out = (float*)d_out;
  char* ws = (char*)d_ws;
  float* qkv = (float*)(ws);                               // (unused now)
  unsigned short* xb = (unsigned short*)(ws + 25165824);   //  8,388,608
  unsigned short* wb = (unsigned short*)(ws + 33554432);   // 12,582,912
  unsigned short* wob = (unsigned short*)(ws + 46137344);  //  8,388,608
  unsigned short* qb = (unsigned short*)(ws + 54525952);   //  8,388,608
  unsigned short* kft = (unsigned short*)(ws + 62914560);  //  2,097,152
  unsigned short* vft = (unsigned short*)(ws + 65011712);  //  2,097,152
  unsigned short* aob = (unsigned short*)(ws + 67108864);  //  8,388,608

  cast3_kernel<<<dim3(3670016 / 256), 256, 0, stream>>>(x, wqkv, wo, xb, wb,
                                                        wob);
  gemm_bt<1, 128, 3><<<dim3(48, 16), 256, 0, stream>>>(
      xb, wb, qkv, vft, cosb, sinb, qb, kft, 2048, 3072, 2048);
  attn_kernel<<<dim3(2048), 256, 0, stream>>>(qb, kft, vft, aob);
  gemm_bt<0, 64, 5><<<dim3(32, 32), 256, 0, stream>>>(
      aob, wob, out, nullptr, nullptr, nullptr, nullptr, nullptr, 2048, 2048,
      2048);
}